// Round 6
// baseline (424.090 us; speedup 1.0000x reference)
//
#include <hip/hip_runtime.h>
#include <hip/hip_bf16.h>

#define EPS 1e-5f

typedef __bf16 bf16x8 __attribute__((ext_vector_type(8)));
typedef float f32x4 __attribute__((ext_vector_type(4)));

// lds dest is WAVE-UNIFORM base; HW scatters lane i -> base + 16*i bytes
__device__ __forceinline__ void async_load16(const __bf16* g, __bf16* lds_base) {
  __builtin_amdgcn_global_load_lds(
      (const __attribute__((address_space(1))) unsigned int*)g,
      (__attribute__((address_space(3))) unsigned int*)lds_base, 16, 0, 0);
}

// ---- workspace layout (total 82,283,520 B; ws_size >= this, proven R0) -----
// xpad  : [16][30][30][512] bf16 @ 0          (14,745,600 B)
// t1pad : [16][58][58][256] bf16 @ 14,745,600 (27,557,888 B)
// wbf   : fragment-linear conv1+sc weights @ 42,303,488 (13,107,200 B)
// w2f   : fragment-linear conv2 weights @ 55,410,688 (1,179,648 B)
// scb   : [16][56][56][256] bf16 @ 56,590,336 (25,690,112 B)
// biasA : 512 f32                @ 82,280,448
// bias2 : 256 f32                @ 82,282,496

// R5 post-mortem: three convB variants identical in total -> stop guessing
// convB-specific causes. R6 applies the ONE measured lever (2-phase drain)
// to BOTH kernels: counted-vmcnt triple-buffer K-loop.
//   iter w: loadB(w+1); stage(w+2); compute(w); s_waitcnt vmcnt(4); s_barrier
// In-order queue [S(w+1)4, B(w+1)8, S(w+2)4]: vmcnt(4) completes exactly
// iter-(w+1)'s needs, leaves S(w+2) in flight. Never vmcnt(0) in loop (T4);
// raw s_barrier (no __syncthreads vmcnt(0) drain). 3 LDS bufs, WAR-safe:
// buf(w+2)%3's readers finished at iter w-1's barrier.

// ---------------- zero borders of xpad + t1pad ------------------------------
__global__ void zero_border_kernel(__bf16* __restrict__ xpad, __bf16* __restrict__ t1pad) {
  const int idx = blockIdx.x * 256 + threadIdx.x;
  uint4 z = (uint4){0u, 0u, 0u, 0u};
  if (idx < 118784) {                       // xpad: 16 b x 116 pos x 64 uint4
    int b = idx / 7424, r = idx % 7424;
    int pos = r >> 6, chunk = r & 63;
    int h, w;
    if (pos < 30)      { h = 0;  w = pos; }
    else if (pos < 60) { h = 29; w = pos - 30; }
    else { int p = pos - 60; h = 1 + (p >> 1); w = (p & 1) * 29; }
    *(uint4*)(xpad + ((size_t)(b * 30 + h) * 30 + w) * 512 + chunk * 8) = z;
  } else if (idx < 235520) {                // t1pad: 16 b x 228 pos x 32 uint4
    int c = idx - 118784;
    int b = c / 7296, r = c % 7296;
    int pos = r >> 5, chunk = r & 31;
    int h, w;
    if (pos < 58)       { h = 0;  w = pos; }
    else if (pos < 116) { h = 57; w = pos - 58; }
    else { int p = pos - 116; h = 1 + (p >> 1); w = (p & 1) * 57; }
    *(uint4*)(t1pad + ((size_t)(b * 58 + h) * 58 + w) * 256 + chunk * 8) = z;
  }
}

// ------- weight prep: coalesced LDS-staged fold+relayout --------------------
__global__ void prep_kernel(const float* __restrict__ w1, const float* __restrict__ g1,
                            const float* __restrict__ b1, const float* __restrict__ m1,
                            const float* __restrict__ v1,
                            const float* __restrict__ wsc, const float* __restrict__ gs,
                            const float* __restrict__ bs, const float* __restrict__ ms,
                            const float* __restrict__ vs,
                            const float* __restrict__ w2, const float* __restrict__ g2,
                            const float* __restrict__ b2, const float* __restrict__ m2,
                            const float* __restrict__ v2,
                            __bf16* __restrict__ wbf, __bf16* __restrict__ w2f,
                            float* __restrict__ biasA, float* __restrict__ bias2) {
  __shared__ float lt[12800];
  __shared__ float sc[16];
  const int bx = blockIdx.x, tid = threadIdx.x;
  if (bx < 512) {
    const int cb = bx >> 4, kb = bx & 15;
    const bool isW1 = cb < 16;
    const int co0 = (isW1 ? cb : cb - 16) * 16;
    const float* src = isW1 ? w1 : wsc;
    if (tid < 16) {
      float gv = isW1 ? g1[co0 + tid] : gs[co0 + tid];
      float vv = isW1 ? v1[co0 + tid] : vs[co0 + tid];
      sc[tid] = gv * rsqrtf(vv + EPS);
    }
    const size_t base = ((size_t)co0 * 512 + kb * 32) * 25;
    for (int it = 0; it < 50; ++it) {
      int idx = tid + it * 256;
      int col = idx / 800, rem = idx - col * 800;
      lt[idx] = src[base + (size_t)col * 12800 + rem];
    }
    __syncthreads();
    for (int it = 0; it < 50; ++it) {
      int o = tid + it * 256;
      int tap = o >> 9, r = o & 511;
      int lane = r >> 3, j = r & 7;
      int col = lane & 15, cil = ((lane >> 4) << 3) + j;
      float v = lt[col * 800 + cil * 25 + tap] * sc[col];
      wbf[(size_t)tap * 262144 + ((size_t)cb * 16 + kb) * 512 + r] = (__bf16)v;
    }
  } else if (bx < 640) {
    const int b2x = bx - 512;
    const int cb = b2x >> 3, kb = b2x & 7;
    const int co0 = cb * 16;
    if (tid < 16) sc[tid] = g2[co0 + tid] * rsqrtf(v2[co0 + tid] + EPS);
    const size_t base = ((size_t)co0 * 256 + kb * 32) * 9;
    for (int it = 0; it < 18; ++it) {
      int idx = tid + it * 256;
      int col = idx / 288, rem = idx - col * 288;
      lt[idx] = w2[base + (size_t)col * 2304 + rem];
    }
    __syncthreads();
    for (int it = 0; it < 18; ++it) {
      int o = tid + it * 256;
      int tap = o >> 9, r = o & 511;
      int lane = r >> 3, j = r & 7;
      int col = lane & 15, cil = ((lane >> 4) << 3) + j;
      float v = lt[col * 288 + cil * 9 + tap] * sc[col];
      w2f[(size_t)tap * 65536 + ((size_t)cb * 8 + kb) * 512 + r] = (__bf16)v;
    }
  } else {
    int c = (bx - 640) * 256 + tid;
    if (c < 256)      biasA[c] = b1[c] - m1[c] * (g1[c] * rsqrtf(v1[c] + EPS));
    else if (c < 512) biasA[c] = bs[c - 256] - ms[c - 256] * (gs[c - 256] * rsqrtf(vs[c - 256] + EPS));
    else              bias2[c - 512] = b2[c - 512] - m2[c - 512] * (g2[c - 512] * rsqrtf(v2[c - 512] + EPS));
  }
}

// ------- x (NCHW f32) -> xpad (padded NHWC bf16 [16][30][30][512]) ----------
__global__ void transpose_kernel(const float* __restrict__ x, __bf16* __restrict__ xpad) {
  __shared__ __bf16 tile[64 * 65];
  const int hw0 = blockIdx.x * 64;
  const int ci0 = blockIdx.y * 64;
  const int b = blockIdx.z;
  const int tid = threadIdx.x;
#pragma unroll
  for (int it = 0; it < 16; ++it) {
    int idx = tid + 256 * it;
    int row = idx >> 6, col = idx & 63;
    int hw = hw0 + col;
    float v = (hw < 784) ? x[(b * 512 + ci0 + row) * 784 + hw] : 0.0f;
    tile[row * 65 + col] = (__bf16)v;
  }
  __syncthreads();
#pragma unroll
  for (int it = 0; it < 16; ++it) {
    int idx = tid + 256 * it;
    int orow = idx >> 6, ocol = idx & 63;
    int hw = hw0 + orow;
    if (hw < 784) {
      int h = hw / 28, w = hw % 28;
      xpad[((b * 30 + 1 + h) * 30 + 1 + w) * 512 + ci0 + ocol] = tile[ocol * 65 + orow];
    }
  }
}

// ---------------- Kernel A v4: counted-vmcnt triple-buffer ------------------
// Geometry identical to R0-proven kernel (1568 blocks, 4 waves, 128x128,
// parity-decomposed). Only the K-loop schedule changes (see header comment).
__global__ __launch_bounds__(256, 3) void convA_kernel(
    const __bf16* __restrict__ xpad, const __bf16* __restrict__ wbf,
    const float* __restrict__ biasA, __bf16* __restrict__ t1pad,
    __bf16* __restrict__ scb) {
  __shared__ alignas(16) __bf16 lA[3][128 * 64];
  const int tid = threadIdx.x;
  const int lane = tid & 63, wv = tid >> 6;
  const int u = blockIdx.x;
  const int mq = (u >> 5) * 8 + (u & 7);      // 0..391
  const int ntile = (u >> 3) & 3;
  const int mtile = mq % 98;
  const int q = mq / 98;
  const int py = q >> 1, px = q & 1;
  const int W = (py ? 2 : 3) * (px ? 2 : 3) * 8;

  const int lrow = lane >> 3;
  const int g = ((lane & 7) ^ lrow) * 8;
  int aoffs[4];
#pragma unroll
  for (int j = 0; j < 4; ++j) {
    int m = mtile * 128 + wv * 32 + j * 8 + lrow;
    int b = m / 784, r = m % 784, hy = r / 28, hx = r % 28;
    aoffs[j] = ((b * 30 + 1 + hy) * 30 + (1 + hx)) * 512 + g;
  }

  const int wm = (wv & 1) * 64, wn = (wv >> 1) * 64;
  const int fr = lane & 15, kh = lane >> 4;
  const int sw = fr & 7;
  const __bf16* bb = wbf + (ntile * 8 + (wv >> 1) * 4) * 8192 + lane * 8;

  f32x4 acc[4][4];
#pragma unroll
  for (int i = 0; i < 4; i++)
#pragma unroll
    for (int n = 0; n < 4; n++) acc[i][n] = (f32x4){0.f, 0.f, 0.f, 0.f};

  auto decode = [&](int w, int& adelta, int& btap, int& kc) {
    int tap = w >> 3;
    kc = w & 7;
    int ty, tx;
    if (px) { ty = tap >> 1; tx = tap & 1; }
    else    { ty = (tap >= 6) ? 2 : ((tap >= 3) ? 1 : 0); tx = tap - ty * 3; }
    int dy = ty - 1 + py, dx = tx - 1 + px;
    int ky = 2 * ty + py, kx = 2 * tx + px;
    adelta = (dy * 30 + dx) * 512;
    btap = (ky * 5 + kx) * 262144;
  };
  auto stage = [&](int adelta, int kc, int buf) {
    __bf16* dst = &lA[buf][wv * 2048];
#pragma unroll
    for (int j = 0; j < 4; ++j)
      async_load16(xpad + (aoffs[j] + adelta + kc * 64), dst + j * 512);
  };
  auto loadB = [&](int btap, int kc, bf16x8* d) {
    const __bf16* bp = bb + btap + kc * 1024;
#pragma unroll
    for (int n = 0; n < 4; ++n) {
      d[n]     = *(const bf16x8*)(bp + n * 8192);
      d[4 + n] = *(const bf16x8*)(bp + n * 8192 + 512);
    }
  };
  auto compute = [&](const __bf16* lds, const bf16x8* bc) {
#pragma unroll
    for (int kk = 0; kk < 2; ++kk) {
      bf16x8 af[4];
#pragma unroll
      for (int f = 0; f < 4; ++f)
        af[f] = *(const bf16x8*)(lds + (wm + f * 16 + fr) * 64 + (((kk * 4 + kh) ^ sw) * 8));
#pragma unroll
      for (int f = 0; f < 4; ++f)
#pragma unroll
        for (int n = 0; n < 4; ++n)
          acc[f][n] = __builtin_amdgcn_mfma_f32_16x16x32_bf16(af[f], bc[kk * 4 + n], acc[f][n], 0, 0, 0);
    }
  };

  bf16x8 b0[8], b1[8];
  {
    int ad, bt, k2;
    decode(0, ad, bt, k2);
    loadB(bt, k2, b0);            // queue: B0(8)
    stage(ad, k2, 0);             // + S0(4)
    decode(1, ad, bt, k2);
    stage(ad, k2, 1);             // + S1(4)
    asm volatile("s_waitcnt vmcnt(4)" ::: "memory");   // B0,S0 done; S1 in flight
    __builtin_amdgcn_s_barrier();
    __builtin_amdgcn_sched_barrier(0);
  }
  for (int w = 0; w < W; w += 2) {
    {   // even sub-iter: compute b0, load b1(w+1), stage(w+2)
      int ad, bt, k2;
      decode(w + 1, ad, bt, k2);
      loadB(bt, k2, b1);
      if (w + 2 < W) { decode(w + 2, ad, bt, k2); stage(ad, k2, (w + 2) % 3); }
      compute(lA[w % 3], b0);
      if (w + 2 < W) asm volatile("s_waitcnt vmcnt(4)" ::: "memory");
      else           asm volatile("s_waitcnt vmcnt(0)" ::: "memory");
      __builtin_amdgcn_s_barrier();
      __builtin_amdgcn_sched_barrier(0);
    }
    {   // odd sub-iter: compute b1, load b0(w+2), stage(w+3)
      int ad, bt, k2;
      if (w + 2 < W) { decode(w + 2, ad, bt, k2); loadB(bt, k2, b0); }
      if (w + 3 < W) { decode(w + 3, ad, bt, k2); stage(ad, k2, (w + 3) % 3); }
      compute(lA[(w + 1) % 3], b1);
      if (w + 2 < W) {
        if (w + 3 < W) asm volatile("s_waitcnt vmcnt(4)" ::: "memory");
        else           asm volatile("s_waitcnt vmcnt(0)" ::: "memory");
        __builtin_amdgcn_s_barrier();
        __builtin_amdgcn_sched_barrier(0);
      }
    }
  }

  // epilogue: C/D layout col(n)=fr, row(m)=kh*4+reg
  const bool isT1 = (ntile < 2);
  int ob[16];
#pragma unroll
  for (int f = 0; f < 4; f++)
#pragma unroll
    for (int r = 0; r < 4; r++) {
      int m = mtile * 128 + wm + f * 16 + kh * 4 + r;
      int b = m / 784, rr = m % 784, hy = rr / 28, hx = rr % 28;
      int oy = 2 * hy + py, ox = 2 * hx + px;
      ob[f * 4 + r] = isT1 ? ((b * 58 + 1 + oy) * 58 + (1 + ox)) * 256
                           : ((b * 56 + oy) * 56 + ox) * 256;
    }
  __bf16* outp = isT1 ? t1pad : scb;
#pragma unroll
  for (int n = 0; n < 4; n++) {
    int co2 = ntile * 128 + wn + n * 16 + fr;
    float bv = biasA[co2];
    int coL = isT1 ? co2 : (co2 - 256);
#pragma unroll
    for (int f = 0; f < 4; f++)
#pragma unroll
      for (int r = 0; r < 4; r++) {
        float v = acc[f][n][r] + bv;
        if (isT1) v = fmaxf(v, 0.0f);
        outp[ob[f * 4 + r] + coL] = (__bf16)v;
      }
  }
}

// ---------------- Kernel B v5: counted-vmcnt triple-buffer ------------------
// Same transform as convA v4. LDS 48KB -> bound 3 (784 blocks / 768 slots,
// small spill generation accepted). W=36 even.
__global__ __launch_bounds__(256, 3) void convB_kernel(
    const __bf16* __restrict__ t1pad, const __bf16* __restrict__ w2f,
    const float* __restrict__ bias2, const __bf16* __restrict__ scb,
    float* __restrict__ out) {
  __shared__ alignas(16) __bf16 lA[3][128 * 64];
  const int tid = threadIdx.x;
  const int lane = tid & 63, wv = tid >> 6;
  const int u = blockIdx.x;
  const int mtile = (u >> 4) * 8 + (u & 7);   // 0..391
  const int ntile = (u >> 3) & 1;
  const int W = 36;

  const int lrow = lane >> 3;
  const int g = ((lane & 7) ^ lrow) * 8;
  int aoffs[4];
#pragma unroll
  for (int j = 0; j < 4; ++j) {
    int m = mtile * 128 + wv * 32 + j * 8 + lrow;
    int b = m / 3136, r = m % 3136, y = r / 56, x = r % 56;
    aoffs[j] = ((b * 58 + 1 + y) * 58 + (1 + x)) * 256 + g;
  }

  const int wm = (wv & 1) * 64, wn = (wv >> 1) * 64;
  const int fr = lane & 15, kh = lane >> 4;
  const int sw = fr & 7;
  const __bf16* bb = w2f + (ntile * 8 + (wv >> 1) * 4) * 4096 + lane * 8;

  f32x4 acc[4][4];
#pragma unroll
  for (int i = 0; i < 4; i++)
#pragma unroll
    for (int n = 0; n < 4; n++) acc[i][n] = (f32x4){0.f, 0.f, 0.f, 0.f};

  auto decode = [&](int w, int& adelta, int& btap, int& kc) {
    int tap = w >> 2;
    kc = w & 3;
    int ty = (tap >= 6) ? 2 : ((tap >= 3) ? 1 : 0);
    int tx = tap - ty * 3;
    adelta = ((ty - 1) * 58 + (tx - 1)) * 256;
    btap = tap * 65536;
  };
  auto stage = [&](int adelta, int kc, int buf) {
    __bf16* dst = &lA[buf][wv * 2048];
#pragma unroll
    for (int j = 0; j < 4; ++j)
      async_load16(t1pad + (aoffs[j] + adelta + kc * 64), dst + j * 512);
  };
  auto loadB = [&](int btap, int kc, bf16x8* d) {
    const __bf16* bp = bb + btap + kc * 1024;
#pragma unroll
    for (int n = 0; n < 4; ++n) {
      d[n]     = *(const bf16x8*)(bp + n * 4096);
      d[4 + n] = *(const bf16x8*)(bp + n * 4096 + 512);
    }
  };
  auto compute = [&](const __bf16* lds, const bf16x8* bc) {
#pragma unroll
    for (int kk = 0; kk < 2; ++kk) {
      bf16x8 af[4];
#pragma unroll
      for (int f = 0; f < 4; ++f)
        af[f] = *(const bf16x8*)(lds + (wm + f * 16 + fr) * 64 + (((kk * 4 + kh) ^ sw) * 8));
#pragma unroll
      for (int f = 0; f < 4; ++f)
#pragma unroll
        for (int n = 0; n < 4; ++n)
          acc[f][n] = __builtin_amdgcn_mfma_f32_16x16x32_bf16(af[f], bc[kk * 4 + n], acc[f][n], 0, 0, 0);
    }
  };

  bf16x8 b0[8], b1[8];
  {
    int ad, bt, k2;
    decode(0, ad, bt, k2);
    loadB(bt, k2, b0);
    stage(ad, k2, 0);
    decode(1, ad, bt, k2);
    stage(ad, k2, 1);
    asm volatile("s_waitcnt vmcnt(4)" ::: "memory");
    __builtin_amdgcn_s_barrier();
    __builtin_amdgcn_sched_barrier(0);
  }
  for (int w = 0; w < W; w += 2) {
    {   // even sub-iter
      int ad, bt, k2;
      decode(w + 1, ad, bt, k2);
      loadB(bt, k2, b1);
      if (w + 2 < W) { decode(w + 2, ad, bt, k2); stage(ad, k2, (w + 2) % 3); }
      compute(lA[w % 3], b0);
      if (w + 2 < W) asm volatile("s_waitcnt vmcnt(4)" ::: "memory");
      else           asm volatile("s_waitcnt vmcnt(0)" ::: "memory");
      __builtin_amdgcn_s_barrier();
      __builtin_amdgcn_sched_barrier(0);
    }
    {   // odd sub-iter
      int ad, bt, k2;
      if (w + 2 < W) { decode(w + 2, ad, bt, k2); loadB(bt, k2, b0); }
      if (w + 3 < W) { decode(w + 3, ad, bt, k2); stage(ad, k2, (w + 3) % 3); }
      compute(lA[(w + 1) % 3], b1);
      if (w + 2 < W) {
        if (w + 3 < W) asm volatile("s_waitcnt vmcnt(4)" ::: "memory");
        else           asm volatile("s_waitcnt vmcnt(0)" ::: "memory");
        __builtin_amdgcn_s_barrier();
        __builtin_amdgcn_sched_barrier(0);
      }
    }
  }

  float bv[4];
#pragma unroll
  for (int n = 0; n < 4; ++n) bv[n] = bias2[ntile * 128 + wn + n * 16 + fr];
#pragma unroll
  for (int f = 0; f < 4; ++f) {
    int m0 = mtile * 128 + wm + f * 16 + kh * 4;
    int b = m0 / 3136, r0 = m0 % 3136;
#pragma unroll
    for (int n = 0; n < 4; ++n) {
      int co = ntile * 128 + wn + n * 16 + fr;
      const __bf16* scp = scb + (b * 3136 + r0) * 256 + co;
      f32x4 v;
#pragma unroll
      for (int r = 0; r < 4; ++r)
        v[r] = fmaxf(acc[f][n][r] + bv[n] + (float)scp[r * 256], 0.0f);
      *(f32x4*)(out + ((b * 256 + co) * 3136 + r0)) = v;
    }
  }
}

// ---------------- launch -----------------------------------------------------
extern "C" void kernel_launch(void* const* d_in, const int* in_sizes, int n_in,
                              void* d_out, int out_size, void* d_ws, size_t ws_size,
                              hipStream_t stream) {
  const float* x   = (const float*)d_in[0];
  const float* w1  = (const float*)d_in[1];
  const float* g1  = (const float*)d_in[2];
  const float* b1  = (const float*)d_in[3];
  const float* m1  = (const float*)d_in[4];
  const float* v1  = (const float*)d_in[5];
  const float* w2  = (const float*)d_in[6];
  const float* g2  = (const float*)d_in[7];
  const float* b2  = (const float*)d_in[8];
  const float* m2  = (const float*)d_in[9];
  const float* v2  = (const float*)d_in[10];
  const float* wsc = (const float*)d_in[11];
  const float* gs  = (const float*)d_in[12];
  const float* bs  = (const float*)d_in[13];
  const float* ms  = (const float*)d_in[14];
  const float* vs  = (const float*)d_in[15];
  float* out = (float*)d_out;

  char* ws = (char*)d_ws;
  __bf16* xpad  = (__bf16*)(ws);                  // 14,745,600 B
  __bf16* t1pad = (__bf16*)(ws + 14745600);       // 27,557,888 B
  __bf16* wbf   = (__bf16*)(ws + 42303488);       // 13,107,200 B
  __bf16* w2f   = (__bf16*)(ws + 55410688);       // 1,179,648 B
  __bf16* scb   = (__bf16*)(ws + 56590336);       // 25,690,112 B
  float* biasA  = (float*)(ws + 82280448);        // 2,048 B
  float* bias2  = (float*)(ws + 82282496);        // 1,024 B

  zero_border_kernel<<<dim3(920), 256, 0, stream>>>(xpad, t1pad);
  prep_kernel<<<dim3(643), 256, 0, stream>>>(w1, g1, b1, m1, v1, wsc, gs, bs, ms, vs,
                                             w2, g2, b2, m2, v2, wbf, w2f, biasA, bias2);
  transpose_kernel<<<dim3(13, 8, 16), 256, 0, stream>>>(x, xpad);
  convA_kernel<<<dim3(1568), 256, 0, stream>>>(xpad, wbf, biasA, t1pad, scb);
  convB_kernel<<<dim3(784), 256, 0, stream>>>(t1pad, w2f, bias2, scb, out);
}

// Round 7
// 399.436 us; speedup vs baseline: 1.0617x; 1.0617x over previous
//
#include <hip/hip_runtime.h>
#include <hip/hip_bf16.h>

#define EPS 1e-5f

typedef __bf16 bf16x8 __attribute__((ext_vector_type(8)));
typedef float f32x4 __attribute__((ext_vector_type(4)));

// lds dest is WAVE-UNIFORM base; HW scatters lane i -> base + 16*i bytes
__device__ __forceinline__ void async_load16(const __bf16* g, __bf16* lds_base) {
  __builtin_amdgcn_global_load_lds(
      (const __attribute__((address_space(1))) unsigned int*)g,
      (__attribute__((address_space(3))) unsigned int*)lds_base, 16, 0, 0);
}

// ---- workspace layout (total 82,283,520 B; ws_size >= this, proven R0) -----
// xpad  : [16][30][30][512] bf16 @ 0          (14,745,600 B)
// t1pad : [16][58][58][256] bf16 @ 14,745,600 (27,557,888 B)
// wbf   : fragment-linear conv1+sc weights @ 42,303,488 (13,107,200 B)
// w2f   : fragment-linear conv2 weights @ 55,410,688 (1,179,648 B)
// scb   : [16][56][56][256] bf16 @ 56,590,336 (25,690,112 B)
// biasA : 512 f32                @ 82,280,448
// bias2 : 256 f32                @ 82,282,496

// R6 post-mortem: counted-vmcnt triple-buffer = -4% (reproduces m131-m141
// null). Reverted to R5. New per-iteration arithmetic: convB stalls ~11kcy/
// iter vs convA 2.8kcy -- only L2-thrash explains it: old convB map gave
// each XCD 49 STRIDE-8-SCATTERED mtiles (6.1MB > 4MB L2) and the single-gen
// phase-locked launch turns misses into synchronized HBM bursts.
// R7 (one variable): convB mtile = (u&7)*49 + (u>>4) -> XCD c owns mtiles
// [49c,49c+49) = EXACTLY 2 batches of t1pad (3.44MB <= 4MB L2). A-sharing
// nt-pair (u, u+8) unchanged: same mtile, same XCD.

// ---------------- zero borders of xpad + t1pad ------------------------------
__global__ void zero_border_kernel(__bf16* __restrict__ xpad, __bf16* __restrict__ t1pad) {
  const int idx = blockIdx.x * 256 + threadIdx.x;
  uint4 z = (uint4){0u, 0u, 0u, 0u};
  if (idx < 118784) {                       // xpad: 16 b x 116 pos x 64 uint4
    int b = idx / 7424, r = idx % 7424;
    int pos = r >> 6, chunk = r & 63;
    int h, w;
    if (pos < 30)      { h = 0;  w = pos; }
    else if (pos < 60) { h = 29; w = pos - 30; }
    else { int p = pos - 60; h = 1 + (p >> 1); w = (p & 1) * 29; }
    *(uint4*)(xpad + ((size_t)(b * 30 + h) * 30 + w) * 512 + chunk * 8) = z;
  } else if (idx < 235520) {                // t1pad: 16 b x 228 pos x 32 uint4
    int c = idx - 118784;
    int b = c / 7296, r = c % 7296;
    int pos = r >> 5, chunk = r & 31;
    int h, w;
    if (pos < 58)       { h = 0;  w = pos; }
    else if (pos < 116) { h = 57; w = pos - 58; }
    else { int p = pos - 116; h = 1 + (p >> 1); w = (p & 1) * 57; }
    *(uint4*)(t1pad + ((size_t)(b * 58 + h) * 58 + w) * 256 + chunk * 8) = z;
  }
}

// ------- weight prep: coalesced LDS-staged fold+relayout --------------------
__global__ void prep_kernel(const float* __restrict__ w1, const float* __restrict__ g1,
                            const float* __restrict__ b1, const float* __restrict__ m1,
                            const float* __restrict__ v1,
                            const float* __restrict__ wsc, const float* __restrict__ gs,
                            const float* __restrict__ bs, const float* __restrict__ ms,
                            const float* __restrict__ vs,
                            const float* __restrict__ w2, const float* __restrict__ g2,
                            const float* __restrict__ b2, const float* __restrict__ m2,
                            const float* __restrict__ v2,
                            __bf16* __restrict__ wbf, __bf16* __restrict__ w2f,
                            float* __restrict__ biasA, float* __restrict__ bias2) {
  __shared__ float lt[12800];
  __shared__ float sc[16];
  const int bx = blockIdx.x, tid = threadIdx.x;
  if (bx < 512) {
    const int cb = bx >> 4, kb = bx & 15;
    const bool isW1 = cb < 16;
    const int co0 = (isW1 ? cb : cb - 16) * 16;
    const float* src = isW1 ? w1 : wsc;
    if (tid < 16) {
      float gv = isW1 ? g1[co0 + tid] : gs[co0 + tid];
      float vv = isW1 ? v1[co0 + tid] : vs[co0 + tid];
      sc[tid] = gv * rsqrtf(vv + EPS);
    }
    const size_t base = ((size_t)co0 * 512 + kb * 32) * 25;
    for (int it = 0; it < 50; ++it) {
      int idx = tid + it * 256;
      int col = idx / 800, rem = idx - col * 800;
      lt[idx] = src[base + (size_t)col * 12800 + rem];
    }
    __syncthreads();
    for (int it = 0; it < 50; ++it) {
      int o = tid + it * 256;
      int tap = o >> 9, r = o & 511;
      int lane = r >> 3, j = r & 7;
      int col = lane & 15, cil = ((lane >> 4) << 3) + j;
      float v = lt[col * 800 + cil * 25 + tap] * sc[col];
      wbf[(size_t)tap * 262144 + ((size_t)cb * 16 + kb) * 512 + r] = (__bf16)v;
    }
  } else if (bx < 640) {
    const int b2x = bx - 512;
    const int cb = b2x >> 3, kb = b2x & 7;
    const int co0 = cb * 16;
    if (tid < 16) sc[tid] = g2[co0 + tid] * rsqrtf(v2[co0 + tid] + EPS);
    const size_t base = ((size_t)co0 * 256 + kb * 32) * 9;
    for (int it = 0; it < 18; ++it) {
      int idx = tid + it * 256;
      int col = idx / 288, rem = idx - col * 288;
      lt[idx] = w2[base + (size_t)col * 2304 + rem];
    }
    __syncthreads();
    for (int it = 0; it < 18; ++it) {
      int o = tid + it * 256;
      int tap = o >> 9, r = o & 511;
      int lane = r >> 3, j = r & 7;
      int col = lane & 15, cil = ((lane >> 4) << 3) + j;
      float v = lt[col * 288 + cil * 9 + tap] * sc[col];
      w2f[(size_t)tap * 65536 + ((size_t)cb * 8 + kb) * 512 + r] = (__bf16)v;
    }
  } else {
    int c = (bx - 640) * 256 + tid;
    if (c < 256)      biasA[c] = b1[c] - m1[c] * (g1[c] * rsqrtf(v1[c] + EPS));
    else if (c < 512) biasA[c] = bs[c - 256] - ms[c - 256] * (gs[c - 256] * rsqrtf(vs[c - 256] + EPS));
    else              bias2[c - 512] = b2[c - 512] - m2[c - 512] * (g2[c - 512] * rsqrtf(v2[c - 512] + EPS));
  }
}

// ------- x (NCHW f32) -> xpad (padded NHWC bf16 [16][30][30][512]) ----------
__global__ void transpose_kernel(const float* __restrict__ x, __bf16* __restrict__ xpad) {
  __shared__ __bf16 tile[64 * 65];
  const int hw0 = blockIdx.x * 64;
  const int ci0 = blockIdx.y * 64;
  const int b = blockIdx.z;
  const int tid = threadIdx.x;
#pragma unroll
  for (int it = 0; it < 16; ++it) {
    int idx = tid + 256 * it;
    int row = idx >> 6, col = idx & 63;
    int hw = hw0 + col;
    float v = (hw < 784) ? x[(b * 512 + ci0 + row) * 784 + hw] : 0.0f;
    tile[row * 65 + col] = (__bf16)v;
  }
  __syncthreads();
#pragma unroll
  for (int it = 0; it < 16; ++it) {
    int idx = tid + 256 * it;
    int orow = idx >> 6, ocol = idx & 63;
    int hw = hw0 + orow;
    if (hw < 784) {
      int h = hw / 28, w = hw % 28;
      xpad[((b * 30 + 1 + h) * 30 + 1 + w) * 512 + ci0 + ocol] = tile[ocol * 65 + orow];
    }
  }
}

// ---------------- Kernel A: conv1 + shortcut conv (parity-decomposed) -------
// R0-proven version: 195us, MfmaUtil 37.7%. 1D grid 1568; A-sharing blocks 8
// ids apart. B software-pipelined in regs (double-buffer b0/b1, unroll x2).
__global__ __launch_bounds__(256, 3) void convA_kernel(
    const __bf16* __restrict__ xpad, const __bf16* __restrict__ wbf,
    const float* __restrict__ biasA, __bf16* __restrict__ t1pad,
    __bf16* __restrict__ scb) {
  __shared__ alignas(16) __bf16 lA[2][128 * 64];
  const int tid = threadIdx.x;
  const int lane = tid & 63, wv = tid >> 6;
  const int u = blockIdx.x;
  const int mq = (u >> 5) * 8 + (u & 7);      // 0..391
  const int ntile = (u >> 3) & 3;
  const int mtile = mq % 98;
  const int q = mq / 98;
  const int py = q >> 1, px = q & 1;
  const int W = (py ? 2 : 3) * (px ? 2 : 3) * 8;

  const int lrow = lane >> 3;
  const int g = ((lane & 7) ^ lrow) * 8;
  int aoffs[4];
#pragma unroll
  for (int j = 0; j < 4; ++j) {
    int m = mtile * 128 + wv * 32 + j * 8 + lrow;
    int b = m / 784, r = m % 784, hy = r / 28, hx = r % 28;
    aoffs[j] = ((b * 30 + 1 + hy) * 30 + (1 + hx)) * 512 + g;
  }

  const int wm = (wv & 1) * 64, wn = (wv >> 1) * 64;
  const int fr = lane & 15, kh = lane >> 4;
  const int sw = fr & 7;
  const __bf16* bb = wbf + (ntile * 8 + (wv >> 1) * 4) * 8192 + lane * 8;

  f32x4 acc[4][4];
#pragma unroll
  for (int i = 0; i < 4; i++)
#pragma unroll
    for (int n = 0; n < 4; n++) acc[i][n] = (f32x4){0.f, 0.f, 0.f, 0.f};

  auto decode = [&](int w, int& adelta, int& btap, int& kc) {
    int tap = w >> 3;
    kc = w & 7;
    int ty, tx;
    if (px) { ty = tap >> 1; tx = tap & 1; }
    else    { ty = (tap >= 6) ? 2 : ((tap >= 3) ? 1 : 0); tx = tap - ty * 3; }
    int dy = ty - 1 + py, dx = tx - 1 + px;
    int ky = 2 * ty + py, kx = 2 * tx + px;
    adelta = (dy * 30 + dx) * 512;
    btap = (ky * 5 + kx) * 262144;
  };
  auto stage = [&](int adelta, int kc, int buf) {
    __bf16* dst = &lA[buf][wv * 2048];
#pragma unroll
    for (int j = 0; j < 4; ++j)
      async_load16(xpad + (aoffs[j] + adelta + kc * 64), dst + j * 512);
  };
  auto loadB = [&](int btap, int kc, bf16x8* d) {
    const __bf16* bp = bb + btap + kc * 1024;
#pragma unroll
    for (int n = 0; n < 4; ++n) {
      d[n]     = *(const bf16x8*)(bp + n * 8192);
      d[4 + n] = *(const bf16x8*)(bp + n * 8192 + 512);
    }
  };
  auto compute = [&](const __bf16* lds, const bf16x8* bc) {
#pragma unroll
    for (int kk = 0; kk < 2; ++kk) {
      bf16x8 af[4];
#pragma unroll
      for (int f = 0; f < 4; ++f)
        af[f] = *(const bf16x8*)(lds + (wm + f * 16 + fr) * 64 + (((kk * 4 + kh) ^ sw) * 8));
#pragma unroll
      for (int f = 0; f < 4; ++f)
#pragma unroll
        for (int n = 0; n < 4; ++n)
          acc[f][n] = __builtin_amdgcn_mfma_f32_16x16x32_bf16(af[f], bc[kk * 4 + n], acc[f][n], 0, 0, 0);
    }
  };

  bf16x8 b0[8], b1[8];
  int adelta, btap, kc;
  decode(0, adelta, btap, kc);
  stage(adelta, kc, 0);
  loadB(btap, kc, b0);
  __syncthreads();
  for (int w = 0; w < W; w += 2) {
    decode(w + 1, adelta, btap, kc);        // w+1 <= W-1 (W even)
    stage(adelta, kc, 1);
    loadB(btap, kc, b1);
    compute(lA[0], b0);
    __syncthreads();
    if (w + 2 < W) {
      decode(w + 2, adelta, btap, kc);
      stage(adelta, kc, 0);
      loadB(btap, kc, b0);
    }
    compute(lA[1], b1);
    __syncthreads();
  }

  // epilogue: C/D layout col(n)=fr, row(m)=kh*4+reg
  const bool isT1 = (ntile < 2);
  int ob[16];
#pragma unroll
  for (int f = 0; f < 4; f++)
#pragma unroll
    for (int r = 0; r < 4; r++) {
      int m = mtile * 128 + wm + f * 16 + kh * 4 + r;
      int b = m / 784, rr = m % 784, hy = rr / 28, hx = rr % 28;
      int oy = 2 * hy + py, ox = 2 * hx + px;
      ob[f * 4 + r] = isT1 ? ((b * 58 + 1 + oy) * 58 + (1 + ox)) * 256
                           : ((b * 56 + oy) * 56 + ox) * 256;
    }
  __bf16* outp = isT1 ? t1pad : scb;
#pragma unroll
  for (int n = 0; n < 4; n++) {
    int co2 = ntile * 128 + wn + n * 16 + fr;
    float bv = biasA[co2];
    int coL = isT1 ? co2 : (co2 - 256);
#pragma unroll
    for (int f = 0; f < 4; f++)
#pragma unroll
      for (int r = 0; r < 4; r++) {
        float v = acc[f][n][r] + bv;
        if (isT1) v = fmaxf(v, 0.0f);
        outp[ob[f * 4 + r] + coL] = (__bf16)v;
      }
  }
}

// ---------------- Kernel B v6: half-iter B dbuf + XCD-chunked mtile map -----
// R5 kernel with ONE change: mtile = (u&7)*49 + (u>>4)  (was (u>>4)*8+(u&7)).
// Under mod-8 XCD dispatch, XCD c owns mtiles [49c,49c+49) = exactly 2
// batches of t1pad (3.44MB <= 4MB per-XCD L2) -> tap re-staging becomes
// L2-resident instead of scattered-6.1MB thrash. A-sharing pair (u,u+8)
// unchanged: same mtile/XCD, nt 0/1.
__global__ __launch_bounds__(256, 4) void convB_kernel(
    const __bf16* __restrict__ t1pad, const __bf16* __restrict__ w2f,
    const float* __restrict__ bias2, const __bf16* __restrict__ scb,
    float* __restrict__ out) {
  __shared__ alignas(16) __bf16 lA[2][128 * 64];
  const int tid = threadIdx.x;
  const int lane = tid & 63, wv = tid >> 6;
  const int u = blockIdx.x;
  const int mtile = (u & 7) * 49 + (u >> 4);  // XCD-chunked: 2 batches/XCD
  const int ntile = (u >> 3) & 1;
  const int W = 36;

  const int lrow = lane >> 3;
  const int g = ((lane & 7) ^ lrow) * 8;
  int aoffs[4];
#pragma unroll
  for (int j = 0; j < 4; ++j) {
    int m = mtile * 128 + wv * 32 + j * 8 + lrow;
    int b = m / 3136, r = m % 3136, y = r / 56, x = r % 56;
    aoffs[j] = ((b * 58 + 1 + y) * 58 + (1 + x)) * 256 + g;
  }

  const int wm = (wv & 1) * 64, wn = (wv >> 1) * 64;
  const int fr = lane & 15, kh = lane >> 4;
  const int sw = fr & 7;
  const __bf16* bb = w2f + (ntile * 8 + (wv >> 1) * 4) * 4096 + lane * 8;

  f32x4 acc[4][4];
#pragma unroll
  for (int i = 0; i < 4; i++)
#pragma unroll
    for (int n = 0; n < 4; n++) acc[i][n] = (f32x4){0.f, 0.f, 0.f, 0.f};

  auto decode = [&](int w, int& adelta, int& btap, int& kc) {
    int tap = w >> 2;
    kc = w & 3;
    int ty = (tap >= 6) ? 2 : ((tap >= 3) ? 1 : 0);
    int tx = tap - ty * 3;
    adelta = ((ty - 1) * 58 + (tx - 1)) * 256;
    btap = tap * 65536;
  };
  auto stage = [&](int adelta, int kc, int buf) {
    __bf16* dst = &lA[buf][wv * 2048];
#pragma unroll
    for (int j = 0; j < 4; ++j)
      async_load16(t1pad + (aoffs[j] + adelta + kc * 64), dst + j * 512);
  };
  auto loadBh = [&](int btap_, int kc_, int kk_, bf16x8* d) {
    const __bf16* bp = bb + btap_ + kc_ * 1024 + kk_ * 512;
#pragma unroll
    for (int n = 0; n < 4; ++n) d[n] = *(const bf16x8*)(bp + n * 4096);
  };
  auto computeh = [&](const __bf16* lds, const bf16x8* bc, int kk) {
    bf16x8 af[4];
#pragma unroll
    for (int f = 0; f < 4; ++f)
      af[f] = *(const bf16x8*)(lds + (wm + f * 16 + fr) * 64 + (((kk * 4 + kh) ^ sw) * 8));
#pragma unroll
    for (int f = 0; f < 4; ++f)
#pragma unroll
      for (int n = 0; n < 4; ++n)
        acc[f][n] = __builtin_amdgcn_mfma_f32_16x16x32_bf16(af[f], bc[n], acc[f][n], 0, 0, 0);
  };

  bf16x8 bc[4], bn[4];
  int adelta, btap, kc;
  decode(0, adelta, btap, kc);
  stage(adelta, kc, 0);
  loadBh(btap, kc, 0, bc);
  __syncthreads();
  int cbtap = btap, ckc = kc;
  for (int w = 0; w < W; ++w) {
    const int buf = w & 1;
    if (w + 1 < W) {
      decode(w + 1, adelta, btap, kc);
      stage(adelta, kc, buf ^ 1);
    }
    loadBh(cbtap, ckc, 1, bn);                 // (w,kk1); covered by kk0 MFMAs
    computeh(lA[buf], bc, 0);
    if (w + 1 < W) loadBh(btap, kc, 0, bc);    // (w+1,kk0); covered by kk1+barrier
    computeh(lA[buf], bn, 1);
    __syncthreads();
    cbtap = btap; ckc = kc;
  }

  float bv[4];
#pragma unroll
  for (int n = 0; n < 4; ++n) bv[n] = bias2[ntile * 128 + wn + n * 16 + fr];
#pragma unroll
  for (int f = 0; f < 4; ++f) {
    int m0 = mtile * 128 + wm + f * 16 + kh * 4;
    int b = m0 / 3136, r0 = m0 % 3136;
#pragma unroll
    for (int n = 0; n < 4; ++n) {
      int co = ntile * 128 + wn + n * 16 + fr;
      const __bf16* scp = scb + (b * 3136 + r0) * 256 + co;
      f32x4 v;
#pragma unroll
      for (int r = 0; r < 4; ++r)
        v[r] = fmaxf(acc[f][n][r] + bv[n] + (float)scp[r * 256], 0.0f);
      *(f32x4*)(out + ((b * 256 + co) * 3136 + r0)) = v;
    }
  }
}

// ---------------- launch -----------------------------------------------------
extern "C" void kernel_launch(void* const* d_in, const int* in_sizes, int n_in,
                              void* d_out, int out_size, void* d_ws, size_t ws_size,
                              hipStream_t stream) {
  const float* x   = (const float*)d_in[0];
  const float* w1  = (const float*)d_in[1];
  const float* g1  = (const float*)d_in[2];
  const float* b1  = (const float*)d_in[3];
  const float* m1  = (const float*)d_in[4];
  const float* v1  = (const float*)d_in[5];
  const float* w2  = (const float*)d_in[6];
  const float* g2  = (const float*)d_in[7];
  const float* b2  = (const float*)d_in[8];
  const float* m2  = (const float*)d_in[9];
  const float* v2  = (const float*)d_in[10];
  const float* wsc = (const float*)d_in[11];
  const float* gs  = (const float*)d_in[12];
  const float* bs  = (const float*)d_in[13];
  const float* ms  = (const float*)d_in[14];
  const float* vs  = (const float*)d_in[15];
  float* out = (float*)d_out;

  char* ws = (char*)d_ws;
  __bf16* xpad  = (__bf16*)(ws);                  // 14,745,600 B
  __bf16* t1pad = (__bf16*)(ws + 14745600);       // 27,557,888 B
  __bf16* wbf   = (__bf16*)(ws + 42303488);       // 13,107,200 B
  __bf16* w2f   = (__bf16*)(ws + 55410688);       // 1,179,648 B
  __bf16* scb   = (__bf16*)(ws + 56590336);       // 25,690,112 B
  float* biasA  = (float*)(ws + 82280448);        // 2,048 B
  float* bias2  = (float*)(ws + 82282496);        // 1,024 B

  zero_border_kernel<<<dim3(920), 256, 0, stream>>>(xpad, t1pad);
  prep_kernel<<<dim3(643), 256, 0, stream>>>(w1, g1, b1, m1, v1, wsc, gs, bs, ms, vs,
                                             w2, g2, b2, m2, v2, wbf, w2f, biasA, bias2);
  transpose_kernel<<<dim3(13, 8, 16), 256, 0, stream>>>(x, xpad);
  convA_kernel<<<dim3(1568), 256, 0, stream>>>(xpad, wbf, biasA, t1pad, scb);
  convB_kernel<<<dim3(784), 256, 0, stream>>>(t1pad, w2f, bias2, scb, out);
}